// Round 1
// baseline (333.440 us; speedup 1.0000x reference)
//
#include <hip/hip_runtime.h>

#define HW 262144
#define WID 512
#define PLANES 48
#define NCH 3
#define PAD 11
#define FW 23
#define XS 92   // xs/hs row stride (floats): 92%32=28 -> per-row bank phase rotation

__device__ __forceinline__ float uniform_f(float v) {
  return __uint_as_float((unsigned)__builtin_amdgcn_readfirstlane((int)__float_as_uint(v)));
}

// ---------- median: single-pass 8192-bin histogram over [-8,8) ----------
__global__ __launch_bounds__(256) void hist1_kernel(const float* __restrict__ x,
                                                    int* __restrict__ ghist1) {
  __shared__ int h[8192];
  const int p = blockIdx.x, s = blockIdx.y, tid = threadIdx.x;
  for (int i = tid; i < 8192; i += 256) h[i] = 0;
  __syncthreads();
  const float4* xv = (const float4*)(x + (size_t)p * HW + (size_t)s * (HW / 16));
#define H1(c) { int b = (int)(((c) + 8.0f) * 512.0f); b = min(max(b, 0), 8191); atomicAdd(&h[b], 1); }
  for (int i = tid; i < HW / 16 / 4; i += 256) {
    float4 v = xv[i];
    H1(v.x); H1(v.y); H1(v.z); H1(v.w);
  }
#undef H1
  __syncthreads();
  int* gh = ghist1 + p * 8192;
  const int st = (s * 512) & 8191;
  for (int k = tid; k < 8192; k += 256) {
    int i = (k + st) & 8191;
    int c = h[i];
    if (c) atomicAdd(&gh[i], c);
  }
}

// ---------- parallel median select (+ k1 prep piggybacked) ----------
__global__ __launch_bounds__(256) void scan_med_kernel(const int* __restrict__ ghist1,
                                                       float* __restrict__ med,
                                                       const float* __restrict__ kern,
                                                       float* __restrict__ k1g) {
  __shared__ int incl[256];
  __shared__ int s_chunk, s_base;
  const int p = blockIdx.x, t = threadIdx.x;
  if (p == 0 && t < FW) k1g[t] = kern[t * FW + PAD] / sqrtf(kern[PAD * FW + PAD]);
  const int* gh = ghist1 + p * 8192;
  int mysum = 0;
#pragma unroll
  for (int j = 0; j < 32; ++j) mysum += gh[t * 32 + j];
  incl[t] = mysum;
  __syncthreads();
  for (int off = 1; off < 256; off <<= 1) {
    int v = (t >= off) ? incl[t - off] : 0;
    __syncthreads();
    incl[t] += v;
    __syncthreads();
  }
  const int rank = 131072;  // 1-based rank of sorted idx (HW-1)/2
  {
    int excl = incl[t] - mysum;
    if (excl < rank && rank <= incl[t]) { s_chunk = t; s_base = rank - excl; }
  }
  __syncthreads();
  if (t < 64) {
    const int c = s_chunk, base = s_base;
    int cnt = (t < 32) ? gh[c * 32 + t] : 0;
    int pfx = cnt;
#pragma unroll
    for (int off = 1; off < 32; off <<= 1) {
      int u = __shfl_up(pfx, off, 64);
      if (t >= off) pfx += u;
    }
    unsigned long long m = __ballot(t < 32 && pfx >= base);
    int bin = c * 32 + (__ffsll((long long)m) - 1);
    if (t == 0) med[p] = -8.0f + ((float)bin + 0.5f) * 0.001953125f + 0.2f;
  }
}

// ---------- separable 23x23 conv + fused res-histogram ----------
// LDS plan (32 KiB union):
//   phase A: xs[86][XS]   masked-input tile (7912 floats)
//   phase B: hs overlay   horizontal conv result written OVER xs (stride XS)
//   phase C: 8192-bin histogram of trunc(res*256)
__global__ __launch_bounds__(256) void conv_kernel(const float* __restrict__ x,
                                                   const float* __restrict__ mask,
                                                   const float* __restrict__ k1g,
                                                   const float* __restrict__ med,
                                                   float* __restrict__ res,
                                                   int* __restrict__ ghist) {
  __shared__ int sbuf[8192];  // 32768 B -> 4-5 blocks/CU
  float* xsf = (float*)sbuf;
  const int z = blockIdx.z;
  const int n = z / NCH;
  const int tbx = blockIdx.x, tby = blockIdx.y;
  const int tid = threadIdx.x;

  float k1[FW];
#pragma unroll
  for (int t = 0; t < FW; ++t) k1[t] = uniform_f(k1g[t]);

  const float m_med = uniform_f(med[z]);
  const int gr0 = tby * 64 - PAD;
  const int gc0 = tbx * 64 - PAD;
  const float* xb = x + (size_t)z * HW;
  const float* mb = mask + (size_t)n * HW;
  for (int i = tid; i < 86 * 86; i += 256) {
    int r = i / 86, c = i - r * 86;
    int gr = min(max(gr0 + r, 0), WID - 1);
    int gc = min(max(gc0 + c, 0), WID - 1);
    int g = gr * WID + gc;
    float xv = xb[g], mv = mb[g];
    xsf[r * XS + c] = fmaf(mv, xv - m_med, m_med);
  }
  __syncthreads();

  // horizontal: 86 rows x 8 groups of 8 outputs = 688 tasks, into registers
  float ah[3][8];
#pragma unroll
  for (int it = 0; it < 3; ++it) {
    const int g = tid + (it << 8);
    if (g < 86 * 8) {
      const int r = g >> 3, c0 = (g & 7) << 3;
      const float* row = &xsf[r * XS + c0];
      float w[32];
#pragma unroll
      for (int q = 0; q < 8; ++q) *(float4*)&w[q * 4] = *(const float4*)(row + q * 4);
#pragma unroll
      for (int j = 0; j < 8; ++j) ah[it][j] = 0.f;
#pragma unroll
      for (int t = 0; t < FW; ++t) {
        const float k = k1[t];
#pragma unroll
        for (int j = 0; j < 8; ++j) ah[it][j] = fmaf(k, w[t + j], ah[it][j]);
      }
    }
  }
  __syncthreads();  // all xs reads complete -> safe to overwrite with hs

#pragma unroll
  for (int it = 0; it < 3; ++it) {
    const int g = tid + (it << 8);
    if (g < 86 * 8) {
      const int r = g >> 3, c0 = (g & 7) << 3;
      *(float4*)&xsf[r * XS + c0] = make_float4(ah[it][0], ah[it][1], ah[it][2], ah[it][3]);
      *(float4*)&xsf[r * XS + c0 + 4] = make_float4(ah[it][4], ah[it][5], ah[it][6], ah[it][7]);
    }
  }
  __syncthreads();

  // vertical: 4x4 micro-tile per thread, reading hs overlay at stride XS
  const int ct = (tid & 15) << 2;
  const int rt = (tid >> 4) << 2;
  float4 acc[4];
#pragma unroll
  for (int j = 0; j < 4; ++j) acc[j] = make_float4(0.f, 0.f, 0.f, 0.f);
#pragma unroll
  for (int tp = 0; tp < 26; ++tp) {
    float4 v = *(const float4*)&xsf[(rt + tp) * XS + ct];
    const int jlo = (tp - 22 > 0) ? (tp - 22) : 0;
    const int jhi = (tp < 3) ? tp : 3;
#pragma unroll
    for (int j = jlo; j <= jhi; ++j) {
      float k = k1[tp - j];
      acc[j].x = fmaf(k, v.x, acc[j].x);
      acc[j].y = fmaf(k, v.y, acc[j].y);
      acc[j].z = fmaf(k, v.z, acc[j].z);
      acc[j].w = fmaf(k, v.w, acc[j].w);
    }
  }

  // re-read x/mask for the central tile (L1/L2-hot) -> recompute xp bit-exactly
  const int orow = tby * 64 + rt;
  const int ocol = tbx * 64 + ct;
  float4 xv[4], mv[4];
#pragma unroll
  for (int j = 0; j < 4; ++j) {
    const size_t g = (size_t)(orow + j) * WID + ocol;
    xv[j] = *(const float4*)(xb + g);
    mv[j] = *(const float4*)(mb + g);
  }
  __syncthreads();  // all hs reads done -> LDS becomes the histogram
  for (int i = tid; i < 8192; i += 256) sbuf[i] = 0;
  __syncthreads();

  float* rb = res + (size_t)z * HW + (size_t)orow * WID + ocol;
#define HADD(c) { int b = (int)((c) * 256.0f) + 4096; b = min(max(b, 0), 8191); atomicAdd(&sbuf[b], 1); }
#pragma unroll
  for (int j = 0; j < 4; ++j) {
    float4 o;
    o.x = 4.0f * (fmaf(mv[j].x, xv[j].x - m_med, m_med) - acc[j].x);
    o.y = 4.0f * (fmaf(mv[j].y, xv[j].y - m_med, m_med) - acc[j].y);
    o.z = 4.0f * (fmaf(mv[j].z, xv[j].z - m_med, m_med) - acc[j].z);
    o.w = 4.0f * (fmaf(mv[j].w, xv[j].w - m_med, m_med) - acc[j].w);
    HADD(o.x); HADD(o.y); HADD(o.z); HADD(o.w);
    *(float4*)(rb + (size_t)j * WID) = o;
  }
#undef HADD
  __syncthreads();

  // merge non-zero bins to per-plane global hist, staggered per block
  int* gh = ghist + z * 8192;
  const int st = ((tby * 8 + tbx) << 7) & 8191;
  for (int k4 = tid; k4 < 2048; k4 += 256) {
    const int i = ((k4 << 2) + st) & 8191;
    const int4 c4 = *(const int4*)&sbuf[i];
    if (c4.x) atomicAdd(&gh[i], c4.x);
    if (c4.y) atomicAdd(&gh[i + 1], c4.y);
    if (c4.z) atomicAdd(&gh[i + 2], c4.z);
    if (c4.w) atomicAdd(&gh[i + 3], c4.w);
  }
}

// ---------- parallel percentile select ----------
__global__ __launch_bounds__(256) void pct_kernel(const int* __restrict__ ghist,
                                                  float* __restrict__ lo_out,
                                                  float* __restrict__ inv_out) {
  __shared__ int incl[256];
  __shared__ int s_chunk, s_base;
  __shared__ float s_v[4];
  const int p = blockIdx.x, t = threadIdx.x;
  const int* gh = ghist + p * 8192;
  int mysum = 0;
#pragma unroll
  for (int j = 0; j < 32; ++j) mysum += gh[t * 32 + j];
  incl[t] = mysum;
  __syncthreads();
  for (int off = 1; off < 256; off <<= 1) {
    int v = (t >= off) ? incl[t - off] : 0;
    __syncthreads();
    incl[t] += v;
    __syncthreads();
  }
  // 1-based ranks: lo -> 7865,7866 (frac .29); hi -> 254279,254280 (frac .71)
  const int ranks[4] = {7865, 7866, 254279, 254280};
#pragma unroll
  for (int r = 0; r < 4; ++r) {
    const int rank = ranks[r];
    int excl = incl[t] - mysum;
    if (excl < rank && rank <= incl[t]) { s_chunk = t; s_base = rank - excl; }
    __syncthreads();
    if (t < 64) {
      const int c = s_chunk, base = s_base;
      int cnt = (t < 32) ? gh[c * 32 + t] : 0;
      int pfx = cnt;
#pragma unroll
      for (int off = 1; off < 32; off <<= 1) {
        int u = __shfl_up(pfx, off, 64);
        if (t >= off) pfx += u;
      }
      unsigned long long m = __ballot(t < 32 && pfx >= base);
      int bin = c * 32 + (__ffsll((long long)m) - 1);
      if (t == 0) s_v[r] = (float)(bin - 4096) * 0.00390625f;
    }
    __syncthreads();
  }
  if (t == 0) {
    const double fl = 0.29, fh = 0.71;
    double lov = (double)s_v[0] + fl * ((double)s_v[1] - (double)s_v[0]);
    double hiv = (double)s_v[2] + fh * ((double)s_v[3] - (double)s_v[2]);
    lo_out[p] = (float)lov;
    inv_out[p] = (float)(1.0 / (hiv - lov));
  }
}

// ---------- final normalize in place (res lives in d_out) ----------
__global__ __launch_bounds__(256) void final_kernel(float* __restrict__ res,
                                                    const float* __restrict__ mask,
                                                    const float* __restrict__ lo,
                                                    const float* __restrict__ inv) {
  const int i = blockIdx.x * 256 + threadIdx.x;
  const int e = i << 2;
  const int z = e >> 18;
  const int n = z / NCH;
  const int hw = e & (HW - 1);
  float4 r = ((const float4*)res)[i];
  float4 m = *(const float4*)(mask + (size_t)n * HW + hw);
  const float l = lo[z];
  const float iv = inv[z];
  float4 o;
  o.x = (r.x - l) * iv * m.x;
  o.y = (r.y - l) * iv * m.y;
  o.z = (r.z - l) * iv * m.z;
  o.w = (r.w - l) * iv * m.w;
  ((float4*)res)[i] = o;
}

extern "C" void kernel_launch(void* const* d_in, const int* in_sizes, int n_in,
                              void* d_out, int out_size, void* d_ws, size_t ws_size,
                              hipStream_t stream) {
  (void)in_sizes; (void)n_in; (void)out_size; (void)ws_size;
  const float* x = (const float*)d_in[0];
  const float* mask = (const float*)d_in[1];
  const float* kern = (const float*)d_in[2];
  float* out = (float*)d_out;  // doubles as res scratch

  int* hist = (int*)d_ws;                 // 48*8192
  int* ghist1 = hist + PLANES * 8192;     // 48*8192
  float* med = (float*)(ghist1 + PLANES * 8192);
  float* lo = med + PLANES;
  float* inv = lo + PLANES;
  float* k1g = inv + PLANES;              // 23 floats

  hipMemsetAsync(hist, 0, (size_t)PLANES * (8192 + 8192) * sizeof(int), stream);
  hist1_kernel<<<dim3(PLANES, 16), 256, 0, stream>>>(x, ghist1);
  scan_med_kernel<<<PLANES, 256, 0, stream>>>(ghist1, med, kern, k1g);
  conv_kernel<<<dim3(8, 8, PLANES), 256, 0, stream>>>(x, mask, k1g, med, out, hist);
  pct_kernel<<<PLANES, 256, 0, stream>>>(hist, lo, inv);
  final_kernel<<<(HW * PLANES / 4 + 255) / 256, 256, 0, stream>>>(out, mask, lo, inv);
}

// Round 2
// 209.569 us; speedup vs baseline: 1.5911x; 1.5911x over previous
//
#include <hip/hip_runtime.h>

#define HW 262144
#define WID 512
#define PLANES 48
#define NCH 3
#define PAD 11
#define FW 23
#define XS 92   // xs/hs row stride (floats): 92%32=28 -> per-row bank phase rotation

__device__ __forceinline__ float uniform_f(float v) {
  return __uint_as_float((unsigned)__builtin_amdgcn_readfirstlane((int)__float_as_uint(v)));
}

// ---------- median: single-pass 8192-bin histogram over [-8,8) ----------
__global__ __launch_bounds__(256) void hist1_kernel(const float* __restrict__ x,
                                                    int* __restrict__ ghist1) {
  __shared__ int h[8192];
  const int p = blockIdx.x, s = blockIdx.y, tid = threadIdx.x;
  for (int i = tid; i < 8192; i += 256) h[i] = 0;
  __syncthreads();
  const float4* xv = (const float4*)(x + (size_t)p * HW + (size_t)s * (HW / 16));
#define H1(c) { int b = (int)(((c) + 8.0f) * 512.0f); b = min(max(b, 0), 8191); atomicAdd(&h[b], 1); }
  for (int i = tid; i < HW / 16 / 4; i += 256) {
    float4 v = xv[i];
    H1(v.x); H1(v.y); H1(v.z); H1(v.w);
  }
#undef H1
  __syncthreads();
  int* gh = ghist1 + p * 8192;
  const int st = (s * 512) & 8191;
  for (int k = tid; k < 8192; k += 256) {
    int i = (k + st) & 8191;
    int c = h[i];
    if (c) atomicAdd(&gh[i], c);
  }
}

// ---------- parallel median select (+ k1 prep piggybacked) ----------
__global__ __launch_bounds__(256) void scan_med_kernel(const int* __restrict__ ghist1,
                                                       float* __restrict__ med,
                                                       const float* __restrict__ kern,
                                                       float* __restrict__ k1g) {
  __shared__ int incl[256];
  __shared__ int s_chunk, s_base;
  const int p = blockIdx.x, t = threadIdx.x;
  if (p == 0 && t < FW) k1g[t] = kern[t * FW + PAD] / sqrtf(kern[PAD * FW + PAD]);
  const int* gh = ghist1 + p * 8192;
  int mysum = 0;
#pragma unroll
  for (int j = 0; j < 32; ++j) mysum += gh[t * 32 + j];
  incl[t] = mysum;
  __syncthreads();
  for (int off = 1; off < 256; off <<= 1) {
    int v = (t >= off) ? incl[t - off] : 0;
    __syncthreads();
    incl[t] += v;
    __syncthreads();
  }
  const int rank = 131072;  // 1-based rank of sorted idx (HW-1)/2
  {
    int excl = incl[t] - mysum;
    if (excl < rank && rank <= incl[t]) { s_chunk = t; s_base = rank - excl; }
  }
  __syncthreads();
  if (t < 64) {
    const int c = s_chunk, base = s_base;
    int cnt = (t < 32) ? gh[c * 32 + t] : 0;
    int pfx = cnt;
#pragma unroll
    for (int off = 1; off < 32; off <<= 1) {
      int u = __shfl_up(pfx, off, 64);
      if (t >= off) pfx += u;
    }
    unsigned long long m = __ballot(t < 32 && pfx >= base);
    int bin = c * 32 + (__ffsll((long long)m) - 1);
    if (t == 0) med[p] = -8.0f + ((float)bin + 0.5f) * 0.001953125f + 0.2f;
  }
}

// ---------- separable 23x23 conv, register-tiled, hs overlaid on xs ----------
// LDS plan (31648 B -> up to 5 blocks/CU):
//   phase A: xs[86][XS]  masked-input tile
//   phase B: horizontal conv into regs; central xp saved to regs
//   phase C: hs overlay written OVER xs (same stride XS)
//   phase D: vertical conv from overlay; epilogue from xp regs
__global__ __launch_bounds__(256) void conv_kernel(const float* __restrict__ x,
                                                   const float* __restrict__ mask,
                                                   const float* __restrict__ k1g,
                                                   const float* __restrict__ med,
                                                   float* __restrict__ res) {
  __shared__ float xs[86 * XS];  // 31648 B
  const int z = blockIdx.z;
  const int n = z / NCH;
  const int tbx = blockIdx.x, tby = blockIdx.y;
  const int tid = threadIdx.x;

  float k1[FW];
#pragma unroll
  for (int t = 0; t < FW; ++t) k1[t] = uniform_f(k1g[t]);

  const float m_med = uniform_f(med[z]);
  const int gr0 = tby * 64 - PAD;
  const int gc0 = tbx * 64 - PAD;
  const float* xb = x + (size_t)z * HW;
  const float* mb = mask + (size_t)n * HW;
  for (int i = tid; i < 86 * 86; i += 256) {
    int r = i / 86, c = i - r * 86;
    int gr = min(max(gr0 + r, 0), WID - 1);
    int gc = min(max(gc0 + c, 0), WID - 1);
    int g = gr * WID + gc;
    float xv = xb[g], mv = mb[g];
    xs[r * XS + c] = fmaf(mv, xv - m_med, m_med);
  }
  __syncthreads();

  // horizontal: 86 rows x 8 groups of 8 outputs = 688 tasks, into registers
  float ah[3][8];
#pragma unroll
  for (int it = 0; it < 3; ++it) {
    const int g = tid + (it << 8);
    if (g < 86 * 8) {
      const int r = g >> 3, c0 = (g & 7) << 3;
      const float* row = &xs[r * XS + c0];
      float w[32];
#pragma unroll
      for (int q = 0; q < 8; ++q) *(float4*)&w[q * 4] = *(const float4*)(row + q * 4);
#pragma unroll
      for (int j = 0; j < 8; ++j) ah[it][j] = 0.f;
#pragma unroll
      for (int t = 0; t < FW; ++t) {
        const float k = k1[t];
#pragma unroll
        for (int j = 0; j < 8; ++j) ah[it][j] = fmaf(k, w[t + j], ah[it][j]);
      }
    }
  }

  // save my central xp values to regs before the overlay destroys xs
  const int ct = (tid & 15) << 2;
  const int rt = (tid >> 4) << 2;
  float4 xpA[4], xpB[4];
#pragma unroll
  for (int j = 0; j < 4; ++j) {
    const float* xr = &xs[(rt + j + PAD) * XS + ct];
    xpA[j] = *(const float4*)(xr + 8);    // .w  = xp at col ct+11
    xpB[j] = *(const float4*)(xr + 12);   // .xyz = xp at cols ct+12..14
  }
  __syncthreads();  // all xs reads complete -> safe to overwrite with hs

#pragma unroll
  for (int it = 0; it < 3; ++it) {
    const int g = tid + (it << 8);
    if (g < 86 * 8) {
      const int r = g >> 3, c0 = (g & 7) << 3;
      *(float4*)&xs[r * XS + c0] = make_float4(ah[it][0], ah[it][1], ah[it][2], ah[it][3]);
      *(float4*)&xs[r * XS + c0 + 4] = make_float4(ah[it][4], ah[it][5], ah[it][6], ah[it][7]);
    }
  }
  __syncthreads();

  // vertical: 4x4 micro-tile per thread, reading hs overlay at stride XS
  float4 acc[4];
#pragma unroll
  for (int j = 0; j < 4; ++j) acc[j] = make_float4(0.f, 0.f, 0.f, 0.f);
#pragma unroll
  for (int tp = 0; tp < 26; ++tp) {
    float4 v = *(const float4*)&xs[(rt + tp) * XS + ct];
    const int jlo = (tp - 22 > 0) ? (tp - 22) : 0;
    const int jhi = (tp < 3) ? tp : 3;
#pragma unroll
    for (int j = jlo; j <= jhi; ++j) {
      float k = k1[tp - j];
      acc[j].x = fmaf(k, v.x, acc[j].x);
      acc[j].y = fmaf(k, v.y, acc[j].y);
      acc[j].z = fmaf(k, v.z, acc[j].z);
      acc[j].w = fmaf(k, v.w, acc[j].w);
    }
  }

  float* rb = res + (size_t)z * HW + (size_t)(tby * 64 + rt) * WID + tbx * 64 + ct;
#pragma unroll
  for (int j = 0; j < 4; ++j) {
    float4 o;
    o.x = 4.0f * (xpA[j].w - acc[j].x);
    o.y = 4.0f * (xpB[j].x - acc[j].y);
    o.z = 4.0f * (xpB[j].y - acc[j].z);
    o.w = 4.0f * (xpB[j].z - acc[j].w);
    *(float4*)(rb + (size_t)j * WID) = o;
  }
}

// ---------- per-plane histogram of trunc(res*256), 8192 bins over [-16,16) ----------
__global__ __launch_bounds__(256) void hist_kernel(const float* __restrict__ res,
                                                   int* __restrict__ ghist) {
  __shared__ int h[8192];
  const int p = blockIdx.x, s = blockIdx.y, tid = threadIdx.x;
  for (int i = tid; i < 8192; i += 256) h[i] = 0;
  __syncthreads();
  const float4* rv = (const float4*)(res + (size_t)p * HW + (size_t)s * (HW / 16));
#define HADD(c) { int b = (int)((c) * 256.0f) + 4096; b = min(max(b, 0), 8191); atomicAdd(&h[b], 1); }
  for (int i = tid; i < HW / 16 / 4; i += 256) {
    float4 v = rv[i];
    HADD(v.x); HADD(v.y); HADD(v.z); HADD(v.w);
  }
#undef HADD
  __syncthreads();
  int* gh = ghist + p * 8192;
  const int st = (s * 512) & 8191;
  for (int k = tid; k < 8192; k += 256) {
    int i = (k + st) & 8191;
    int c = h[i];
    if (c) atomicAdd(&gh[i], c);
  }
}

// ---------- parallel percentile select ----------
__global__ __launch_bounds__(256) void pct_kernel(const int* __restrict__ ghist,
                                                  float* __restrict__ lo_out,
                                                  float* __restrict__ inv_out) {
  __shared__ int incl[256];
  __shared__ int s_chunk, s_base;
  __shared__ float s_v[4];
  const int p = blockIdx.x, t = threadIdx.x;
  const int* gh = ghist + p * 8192;
  int mysum = 0;
#pragma unroll
  for (int j = 0; j < 32; ++j) mysum += gh[t * 32 + j];
  incl[t] = mysum;
  __syncthreads();
  for (int off = 1; off < 256; off <<= 1) {
    int v = (t >= off) ? incl[t - off] : 0;
    __syncthreads();
    incl[t] += v;
    __syncthreads();
  }
  // 1-based ranks: lo -> 7865,7866 (frac .29); hi -> 254279,254280 (frac .71)
  const int ranks[4] = {7865, 7866, 254279, 254280};
#pragma unroll
  for (int r = 0; r < 4; ++r) {
    const int rank = ranks[r];
    int excl = incl[t] - mysum;
    if (excl < rank && rank <= incl[t]) { s_chunk = t; s_base = rank - excl; }
    __syncthreads();
    if (t < 64) {
      const int c = s_chunk, base = s_base;
      int cnt = (t < 32) ? gh[c * 32 + t] : 0;
      int pfx = cnt;
#pragma unroll
      for (int off = 1; off < 32; off <<= 1) {
        int u = __shfl_up(pfx, off, 64);
        if (t >= off) pfx += u;
      }
      unsigned long long m = __ballot(t < 32 && pfx >= base);
      int bin = c * 32 + (__ffsll((long long)m) - 1);
      if (t == 0) s_v[r] = (float)(bin - 4096) * 0.00390625f;
    }
    __syncthreads();
  }
  if (t == 0) {
    const double fl = 0.29, fh = 0.71;
    double lov = (double)s_v[0] + fl * ((double)s_v[1] - (double)s_v[0]);
    double hiv = (double)s_v[2] + fh * ((double)s_v[3] - (double)s_v[2]);
    lo_out[p] = (float)lov;
    inv_out[p] = (float)(1.0 / (hiv - lov));
  }
}

// ---------- final normalize in place (res lives in d_out) ----------
__global__ __launch_bounds__(256) void final_kernel(float* __restrict__ res,
                                                    const float* __restrict__ mask,
                                                    const float* __restrict__ lo,
                                                    const float* __restrict__ inv) {
  const int i = blockIdx.x * 256 + threadIdx.x;
  const int e = i << 2;
  const int z = e >> 18;
  const int n = z / NCH;
  const int hw = e & (HW - 1);
  float4 r = ((const float4*)res)[i];
  float4 m = *(const float4*)(mask + (size_t)n * HW + hw);
  const float l = lo[z];
  const float iv = inv[z];
  float4 o;
  o.x = (r.x - l) * iv * m.x;
  o.y = (r.y - l) * iv * m.y;
  o.z = (r.z - l) * iv * m.z;
  o.w = (r.w - l) * iv * m.w;
  ((float4*)res)[i] = o;
}

extern "C" void kernel_launch(void* const* d_in, const int* in_sizes, int n_in,
                              void* d_out, int out_size, void* d_ws, size_t ws_size,
                              hipStream_t stream) {
  (void)in_sizes; (void)n_in; (void)out_size; (void)ws_size;
  const float* x = (const float*)d_in[0];
  const float* mask = (const float*)d_in[1];
  const float* kern = (const float*)d_in[2];
  float* out = (float*)d_out;  // doubles as res scratch

  int* hist = (int*)d_ws;                 // 48*8192
  int* ghist1 = hist + PLANES * 8192;     // 48*8192
  float* med = (float*)(ghist1 + PLANES * 8192);
  float* lo = med + PLANES;
  float* inv = lo + PLANES;
  float* k1g = inv + PLANES;              // 23 floats

  hipMemsetAsync(hist, 0, (size_t)PLANES * (8192 + 8192) * sizeof(int), stream);
  hist1_kernel<<<dim3(PLANES, 16), 256, 0, stream>>>(x, ghist1);
  scan_med_kernel<<<PLANES, 256, 0, stream>>>(ghist1, med, kern, k1g);
  conv_kernel<<<dim3(8, 8, PLANES), 256, 0, stream>>>(x, mask, k1g, med, out);
  hist_kernel<<<dim3(PLANES, 16), 256, 0, stream>>>(out, hist);
  pct_kernel<<<PLANES, 256, 0, stream>>>(hist, lo, inv);
  final_kernel<<<(HW * PLANES / 4 + 255) / 256, 256, 0, stream>>>(out, mask, lo, inv);
}